// Round 7
// baseline (265.812 us; speedup 1.0000x reference)
//
#include <hip/hip_runtime.h>
#include <hip/hip_bf16.h>
#include <stdint.h>

// ---------------------------------------------------------------------------
// Self-attention, B=4 S=2048 D=1024, fp32 in/out, fp16 MFMA compute.
// R7: LDS-BW analysis showed 64x64 wave tiles cap MfmaUtil at ~30% (measured
// 33%). Switch to v_mfma_f32_32x32x16_f16 with 128x64 wave tiles:
// 42.7 FLOP per LDS byte (vs 32), per-CU LDS demand ~38 B/kFLOP -> ceiling
// ~1.4 PF. Universal GEMM: 128 threads = 2 waves (wc in {0,1}), block tile
// 128x128, BK=64, acc 4x2x16 = 128 VGPR/lane.
// Staging: global_load_lds width=16, XOR chunk swizzle (phys = c ^ (row&7)).
// bm-fastest grid for XCD L2 A-panel sharing (R4: FETCH 150->42 MB).
//   0) cvt: x,w -> fp16
//   1) proj z=3: q,k row-major fp16; z==2 -> vt[b][d][s] via LDS transpose
//   2) scores fp16 (z=batch)   3) softmax in place   4) out fp32
// ---------------------------------------------------------------------------

typedef __attribute__((ext_vector_type(8)))  _Float16 f16x8;
typedef __attribute__((ext_vector_type(4)))  float    f32x4;
typedef __attribute__((ext_vector_type(16))) float    f32x16;
typedef __attribute__((ext_vector_type(4)))  unsigned short u16x4;

__device__ inline unsigned short f2h(float f) {
    union { _Float16 h; unsigned short u; } x;
    x.h = (_Float16)f;   // RNE
    return x.u;
}
__device__ inline float h2f(unsigned short u) {
    union { unsigned short u; _Float16 h; } x;
    x.u = u;
    return (float)x.h;
}

__device__ inline void async16(const unsigned short* g, unsigned short* l) {
    __builtin_amdgcn_global_load_lds(
        (__attribute__((address_space(1))) void*)g,
        (__attribute__((address_space(3))) void*)l, 16, 0, 0);
}

// MODE 0: proj. z<2 -> fp16 row-major into C (+z*sCz); z==2 -> vt transpose
//         into C2 (vt[b][d][s], ld 2048, batch stride 2^21).
// MODE 1: fp16 row-major into C (scores).
// MODE 2: fp32 row-major into C (final out).
template <int MODE>
__global__ __launch_bounds__(128, 2)
void gemm32(const unsigned short* __restrict__ A,
            const unsigned short* __restrict__ B,
            void* __restrict__ C, void* __restrict__ C2,
            int K, int ldA, int ldB, int ldC,
            long sAz, long sBz, long sCz)
{
    __shared__ __align__(16) unsigned short smem[2 * 128 * 64];  // 32 KB
    unsigned short* As = smem;
    unsigned short* Bs = smem + 128 * 64;

    const int tid  = threadIdx.x;
    const int lane = tid & 63;
    const int wc   = tid >> 6;            // 2 waves: col half
    const int l31  = lane & 31;           // m/n within 32x32
    const int h    = lane >> 5;           // k-half selector
    const int bm   = blockIdx.x, bn = blockIdx.y, z = blockIdx.z; // bm fastest

    const unsigned short* Az = A + (long)z * sAz;
    const unsigned short* Bz = B + (long)z * sBz;

    // staging: 1024 chunks (16B) per operand tile (128 rows x 8 slots);
    // LDS slot l holds logical k-chunk (l&7)^(row&7), row = l>>3.
    // Thread t stages slots l = t + 128*i, i in [0,8).
    const unsigned short* gA[8];
    const unsigned short* gB[8];
#pragma unroll
    for (int i = 0; i < 8; ++i) {
        const int l = tid + 128 * i;
        const int r = l >> 3;
        const int c = (l & 7) ^ (r & 7);
        gA[i] = Az + (long)(bm * 128 + r) * ldA + c * 8;
        gB[i] = Bz + (long)(bn * 128 + r) * ldB + c * 8;
    }

    f32x16 acc[4][2];
#pragma unroll
    for (int i = 0; i < 4; ++i)
#pragma unroll
        for (int j = 0; j < 2; ++j)
            acc[i][j] = (f32x16)(0.f);

    const int fr = lane & 7;   // row&7 for fragment de-swizzle (rows = l31)

    for (int k0 = 0; k0 < K; k0 += 64) {
#pragma unroll
        for (int i = 0; i < 8; ++i) async16(gA[i], &As[(tid + 128 * i) * 8]);
#pragma unroll
        for (int i = 0; i < 8; ++i) async16(gB[i], &Bs[(tid + 128 * i) * 8]);
#pragma unroll
        for (int i = 0; i < 8; ++i) { gA[i] += 64; gB[i] += 64; }
        __syncthreads();   // drains vmcnt -> tiles visible in LDS

#pragma unroll
        for (int s = 0; s < 4; ++s) {           // 4 k16-steps
            const int pc = (((s << 1) + h) ^ fr) * 8;   // phys chunk offset
            f16x8 af[4], bf[2];
#pragma unroll
            for (int mt = 0; mt < 4; ++mt)
                af[mt] = *(const f16x8*)&As[(mt * 32 + l31) * 64 + pc];
#pragma unroll
            for (int nt = 0; nt < 2; ++nt)
                bf[nt] = *(const f16x8*)&Bs[(wc * 64 + nt * 32 + l31) * 64 + pc];
#pragma unroll
            for (int mt = 0; mt < 4; ++mt)
#pragma unroll
                for (int nt = 0; nt < 2; ++nt)
                    acc[mt][nt] = __builtin_amdgcn_mfma_f32_32x32x16_f16(
                        af[mt], bf[nt], acc[mt][nt], 0, 0, 0);
        }
        __syncthreads();   // LDS reusable
    }

    // C/D layout (32x32): col = l31, row = (reg&3) + 8*(reg>>2) + 4*h
    const int col_base = bn * 128 + wc * 64;

    if (MODE != 0 || z < 2) {
        const int row_base = bm * 128;
        const long zC = (long)z * sCz;
#pragma unroll
        for (int mt = 0; mt < 4; ++mt)
#pragma unroll
            for (int nt = 0; nt < 2; ++nt)
#pragma unroll
                for (int g = 0; g < 4; ++g)
#pragma unroll
                    for (int r = 0; r < 4; ++r) {
                        const int reg = g * 4 + r;
                        const int row = row_base + mt * 32 + 4 * h + 8 * g + r;
                        const int col = col_base + nt * 32 + l31;
                        if (MODE == 2)
                            ((float*)C)[zC + (long)row * ldC + col] =
                                acc[mt][nt][reg];
                        else
                            ((unsigned short*)C)[zC + (long)row * ldC + col] =
                                f2h(acc[mt][nt][reg]);
                    }
    } else {
        // vt transpose: phases p = wc. T[col 64][row 128], pitch 136 halves
        // (272 B rows keep 16B alignment); aliases As/Bs after final barrier.
        unsigned short* T = smem;   // 64*136 = 8704 halves <= 16384
#pragma unroll
        for (int p = 0; p < 2; ++p) {
            __syncthreads();
            if (wc == p) {
#pragma unroll
                for (int mt = 0; mt < 4; ++mt)
#pragma unroll
                    for (int nt = 0; nt < 2; ++nt)
#pragma unroll
                        for (int g = 0; g < 4; ++g) {
                            const int col_l = nt * 32 + l31;           // 0..63
                            const int r0 = mt * 32 + 4 * h + 8 * g;    // 0..124
                            u16x4 pk = {f2h(acc[mt][nt][g * 4 + 0]),
                                        f2h(acc[mt][nt][g * 4 + 1]),
                                        f2h(acc[mt][nt][g * 4 + 2]),
                                        f2h(acc[mt][nt][g * 4 + 3])};
                            *(u16x4*)&T[col_l * 136 + r0] = pk;
                        }
            }
            __syncthreads();
            // copy out: 64 d-rows x 128 tokens; thread t: c = t>>1, 64 halves
            const int c  = tid >> 1;
            const int j0 = (tid & 1) * 64;
            const int tok0 = bm * 128;            // 128-row tile, 2048%128==0
            const int bb = tok0 >> 11;
            const int s0 = (tok0 & 2047) + j0;
            unsigned short* dst = (unsigned short*)C2 + (long)bb * 2097152 +
                                  (long)(bn * 128 + p * 64 + c) * 2048 + s0;
            const unsigned short* srcT = &T[c * 136 + j0];
#pragma unroll
            for (int i = 0; i < 8; ++i)
                *(f16x8*)(dst + i * 8) = *(const f16x8*)(srcT + i * 8);
        }
    }
}

// fused fp32 -> fp16 conversion: blocks [0,4096) -> x, [4096,5632) -> weights
__global__ __launch_bounds__(256)
void cvt_all(const float* __restrict__ x, const float* __restrict__ w0,
             const float* __restrict__ w1, const float* __restrict__ w2,
             unsigned short* __restrict__ xh, unsigned short* __restrict__ wh)
{
    const int bid = blockIdx.x;
    const float* s;
    unsigned short* d;
    long i;
    if (bid < 4096) {
        s = x; d = xh;
        i = ((long)bid * 256 + threadIdx.x) * 8;
    } else {
        const int wid = bid - 4096;          // [0,1536)
        const int w = wid >> 9;              // weight index
        s = (w == 0) ? w0 : (w == 1) ? w1 : w2;
        d = wh + (long)w * 1048576;
        i = ((long)(wid & 511) * 256 + threadIdx.x) * 8;
    }
    f32x4 a = *(const f32x4*)(s + i);
    f32x4 b = *(const f32x4*)(s + i + 4);
    union { unsigned short u[8]; f16x8 v; } t;
#pragma unroll
    for (int j = 0; j < 4; ++j) { t.u[j] = f2h(a[j]); t.u[4 + j] = f2h(b[j]); }
    *(f16x8*)(d + i) = t.v;
}

// in-place fp16 row softmax: row = 2048 fp16, one block per row.
__global__ __launch_bounds__(256)
void softmax16(unsigned short* __restrict__ sc)
{
    const long row = blockIdx.x;
    unsigned short* srow = sc + row * 2048;
    const int tid = threadIdx.x;

    union { u16x4 p[2]; unsigned short u[8]; } in;
    in.p[0] = *(const u16x4*)(srow + tid * 8);
    in.p[1] = *(const u16x4*)(srow + tid * 8 + 4);
    float v[8];
#pragma unroll
    for (int i = 0; i < 8; ++i) v[i] = h2f(in.u[i]);

    float m = v[0];
#pragma unroll
    for (int i = 1; i < 8; ++i) m = fmaxf(m, v[i]);
#pragma unroll
    for (int off = 32; off; off >>= 1) m = fmaxf(m, __shfl_xor(m, off));

    __shared__ float redm[4], reds[4];
    if ((tid & 63) == 0) redm[tid >> 6] = m;
    __syncthreads();
    m = fmaxf(fmaxf(redm[0], redm[1]), fmaxf(redm[2], redm[3]));

    float s = 0.f;
#pragma unroll
    for (int i = 0; i < 8; ++i) { v[i] = __expf(v[i] - m); s += v[i]; }
#pragma unroll
    for (int off = 32; off; off >>= 1) s += __shfl_xor(s, off);
    if ((tid & 63) == 0) reds[tid >> 6] = s;
    __syncthreads();
    s = reds[0] + reds[1] + reds[2] + reds[3];

    const float inv = 1.f / s;
    union { unsigned short u[8]; f16x8 w; } t;
#pragma unroll
    for (int i = 0; i < 8; ++i) t.u[i] = f2h(v[i] * inv);
    *(f16x8*)(srow + tid * 8) = t.w;
}

extern "C" void kernel_launch(void* const* d_in, const int* in_sizes, int n_in,
                              void* d_out, int out_size, void* d_ws, size_t ws_size,
                              hipStream_t stream)
{
    const float* x  = (const float*)d_in[0];
    const float* wq = (const float*)d_in[1];
    const float* wk = (const float*)d_in[2];
    const float* wv = (const float*)d_in[3];
    float* out = (float*)d_out;

    // batched: [sc fp16 33.5MB (aliases xh 16.8 | wh 6.3)] [q][k][vt] = 83.9MB
    // looped:  [xh|wh 23.1MB (per-batch sc fp16 8.4MB aliases xh)][q][k][vt]
    char* base = (char*)d_ws;
    const bool batched = (ws_size >= 88080384UL);   // 84 MB

    unsigned short* xh = (unsigned short*)base;
    unsigned short* wh = (unsigned short*)(base + 16777216);
    unsigned short* sc = (unsigned short*)base;
    unsigned short* q  = (unsigned short*)(base + (batched ? 33554432 : 23068672));
    unsigned short* k  = q + 8388608;
    unsigned short* vt = k + 8388608;

    // 0) conversions (single dispatch)
    cvt_all<<<5632, 256, 0, stream>>>(x, wq, wk, wv, xh, wh);

    // 1) fused projections: M=8192 N=1024 K=1024; z=0,1 -> q,k; z=2 -> vt
    gemm32<0><<<dim3(64, 8, 3), 128, 0, stream>>>(
        xh, wh, q, vt, 1024, 1024, 1024, 1024, 0L, 1048576L, 8388608L);

    if (batched) {
        // 2) scores fp16: M=N=2048 K=1024, z=batch; (16,16,4)=1024 blocks
        gemm32<1><<<dim3(16, 16, 4), 128, 0, stream>>>(
            q, k, sc, nullptr, 1024, 1024, 1024, 2048,
            2097152L, 2097152L, 4194304L);
        // 3) softmax in place (8192 rows, fp16->fp16)
        softmax16<<<8192, 256, 0, stream>>>(sc);
        // 4) out: M=2048 N=1024 K=2048; (16,8,4)=512 blocks
        gemm32<2><<<dim3(16, 8, 4), 128, 0, stream>>>(
            sc, vt, out, nullptr, 2048, 2048, 2048, 1024,
            4194304L, 2097152L, 2097152L);
    } else {
        for (int b = 0; b < 4; ++b) {
            gemm32<1><<<dim3(16, 16, 1), 128, 0, stream>>>(
                q + (long)b * 2097152, k + (long)b * 2097152, sc, nullptr,
                1024, 1024, 1024, 2048, 0L, 0L, 0L);
            softmax16<<<2048, 256, 0, stream>>>(sc);
            gemm32<2><<<dim3(16, 8, 1), 128, 0, stream>>>(
                sc, vt + (long)b * 2097152, out + (long)b * 2097152, nullptr,
                2048, 2048, 2048, 1024, 0L, 0L, 0L);
        }
    }
}